// Round 4
// baseline (590.564 us; speedup 1.0000x reference)
//
#include <hip/hip_runtime.h>

#define CC 19
#define NPOS 361
#define NPAD 384
#define DIM 256
#define TKEY 32
#define NTILES 12

using bf16x8 = __attribute__((ext_vector_type(8))) short;
using floatx4 = __attribute__((ext_vector_type(4))) float;

__device__ __forceinline__ unsigned short f2bf(float f) {
  unsigned u = __builtin_bit_cast(unsigned, f);
  u += 0x7fffu + ((u >> 16) & 1u);
  return (unsigned short)(u >> 16);
}

// fused conversion: x (zero-padded 361->384 rows) + all weights, f32 -> bf16
__global__ void conv_all_kernel(const float* __restrict__ x,
                                const float* __restrict__ w_in,
                                const float* __restrict__ w_out,
                                const float* __restrict__ w_fuse,
                                unsigned short* __restrict__ ws) {
  const int j = blockIdx.x * 256 + threadIdx.x;
  float4 v = make_float4(0.f, 0.f, 0.f, 0.f);
  unsigned short* dst;
  if (j < 786432) {
    const int row = j >> 6;
    const int off = (j & 63) << 2;
    const int b = row / NPAD;
    const int r = row - b * NPAD;
    if (r < NPOS) v = *(const float4*)&x[(b * NPOS + r) * DIM + off];
    dst = &ws[row * DIM + off];
  } else if (j < 1720320) {
    const int k = j - 786432;
    v = *(const float4*)&w_in[k << 2];
    dst = &ws[3145728 + (k << 2)];
  } else if (j < 2031616) {
    const int k = j - 1720320;
    v = *(const float4*)&w_out[k << 2];
    dst = &ws[6881280 + (k << 2)];
  } else {
    const int k = j - 2031616;
    v = *(const float4*)&w_fuse[k << 2];
    dst = &ws[8126464 + (k << 2)];
  }
  ushort4 o;
  o.x = f2bf(v.x); o.y = f2bf(v.y); o.z = f2bf(v.z); o.w = f2bf(v.w);
  *(ushort4*)dst = o;
}

// Attention kernel: one block per (c, b, head-group g). 4 waves = 4 heads.
// Computes Q (128-col slice), K/V (128-col slices), flash attention, writes
// attention-out (19 rows x 128 cols, f32) into d_out as staging.
// LDS 44.5KB static; reg target <=170 via launch_bounds(256,3) -> 12 waves/CU
// = 3 co-resident blocks (R3 showed 8-wave blocks can't pack into the
// ~164-reg 12-wave cap -> 1 block/CU).
__launch_bounds__(256, 3)
__global__ void attn_kernel(const float* __restrict__ b_in,
                            const unsigned short* __restrict__ xbf,
                            const unsigned short* __restrict__ wibf,
                            float* __restrict__ out) {
  // XCD swizzle: same channel -> same XCD (1216 = 8 * 152 blocks)
  const int bid = blockIdx.x;
  const int xcd = bid & 7;
  const int slot = bid >> 3;
  int c, b, g;
  if (slot < 128) {
    c = ((slot >> 6) << 3) + xcd;       // channels 0..15
    const int r = slot & 63;
    b = r & 31; g = r >> 5;
  } else {
    const int widx = ((slot - 128) << 3) + xcd;  // 0..191
    c = 16 + (widx >> 6);               // channels 16..18
    const int r = widx & 63;
    b = r & 31; g = r >> 5;
  }

  const int tid = threadIdx.x;
  const int w = tid >> 6;        // wave 0..3; head = g*4 + w
  const int lane = tid & 63;
  const int quad = lane >> 4;
  const int l16 = lane & 15;
  const int el = w * 32;         // head's e-offset within the 128-col group

  __shared__ unsigned short sQ[32 * 136];
  __shared__ unsigned short sK[32 * 136];
  __shared__ unsigned short sVT[128 * 40];
  __shared__ unsigned short sXP[32 * 264];   // sX tile, overlaid by per-wave sP
  unsigned short* sP = sXP + w * 1280;       // 32 x 40, wave-private

  const float scale = 0.17677669529663687f;  // 1/sqrt(32)
  const floatx4 fzero = {0.f, 0.f, 0.f, 0.f};

  // ---------------- Q = xq @ wq^T + bq (scaled) -> sQ [32][136]
  {
#pragma unroll
    for (int mt = 0; mt < 2; ++mt) {
      const int xrow = b * NPAD + c * CC + mt * 16 + l16;
      bf16x8 a8[8];
#pragma unroll
      for (int k = 0; k < 8; ++k)
        a8[k] = *(const bf16x8*)&xbf[xrow * DIM + k * 32 + quad * 8];
#pragma unroll
      for (int nt2 = 0; nt2 < 2; ++nt2) {
        const int wr = c * 768 + g * 128 + el + nt2 * 16 + l16;
        floatx4 acc = fzero;
#pragma unroll
        for (int k = 0; k < 8; ++k) {
          bf16x8 b8 = *(const bf16x8*)&wibf[wr * DIM + k * 32 + quad * 8];
          acc = __builtin_amdgcn_mfma_f32_16x16x32_bf16(a8[k], b8, acc, 0, 0, 0);
        }
        const float bias = b_in[wr];
#pragma unroll
        for (int r = 0; r < 4; ++r)
          sQ[(mt * 16 + quad * 4 + r) * 136 + el + nt2 * 16 + l16] =
              f2bf((acc[r] + bias) * scale);
      }
    }
  }

  floatx4 o_acc[2][2];
  float m_run[2][4], l_run[2][4];
#pragma unroll
  for (int mt = 0; mt < 2; ++mt) {
#pragma unroll
    for (int nt2 = 0; nt2 < 2; ++nt2) o_acc[mt][nt2] = fzero;
#pragma unroll
    for (int r = 0; r < 4; ++r) { m_run[mt][r] = -1e30f; l_run[mt][r] = 0.f; }
  }

  for (int t = 0; t < NTILES; ++t) {
    const int t0 = t * TKEY;
    __syncthreads();  // prev-tile reads of sK/sVT/sP(sXP) done

    // stage x tile [32][264] bf16 (8 bf16x8 per thread? 32*256/256 = 32 elts)
#pragma unroll
    for (int it = 0; it < 4; ++it) {
      const int cc2 = tid + it * 256;
      const int row = cc2 >> 5;
      const int col = (cc2 & 31) * 8;
      *(bf16x8*)&sXP[row * 264 + col] = *(const bf16x8*)&xbf[(b * NPAD + t0 + row) * DIM + col];
    }
    __syncthreads();

    // ---------------- K/V slice projection: 64 weight-rows per wave
    {
      floatx4 acc[4][2];
#pragma unroll
      for (int m4 = 0; m4 < 4; ++m4)
#pragma unroll
        for (int n4 = 0; n4 < 2; ++n4) acc[m4][n4] = fzero;

      // waves 0,1 -> K slice rows; waves 2,3 -> V slice rows
      const int wrow0 = (w < 2) ? (c * 768 + 256 + g * 128 + w * 64)
                                : (c * 768 + 512 + g * 128 + (w - 2) * 64);
      bf16x8 abuf[2][4];
#pragma unroll
      for (int m4 = 0; m4 < 4; ++m4)
        abuf[0][m4] = *(const bf16x8*)&wibf[(wrow0 + m4 * 16 + l16) * DIM + quad * 8];
#pragma unroll
      for (int k = 0; k < 8; ++k) {
        if (k < 7) {
#pragma unroll
          for (int m4 = 0; m4 < 4; ++m4)
            abuf[(k + 1) & 1][m4] =
                *(const bf16x8*)&wibf[(wrow0 + m4 * 16 + l16) * DIM + (k + 1) * 32 + quad * 8];
        }
        bf16x8 bfr[2];
#pragma unroll
        for (int n4 = 0; n4 < 2; ++n4)
          bfr[n4] = *(const bf16x8*)&sXP[(n4 * 16 + l16) * 264 + k * 32 + quad * 8];
#pragma unroll
        for (int m4 = 0; m4 < 4; ++m4)
#pragma unroll
          for (int n4 = 0; n4 < 2; ++n4)
            acc[m4][n4] = __builtin_amdgcn_mfma_f32_16x16x32_bf16(abuf[k & 1][m4], bfr[n4],
                                                                  acc[m4][n4], 0, 0, 0);
      }
#pragma unroll
      for (int m4 = 0; m4 < 4; ++m4) {
        const float4 bv = *(const float4*)&b_in[wrow0 + m4 * 16 + quad * 4];
        const float ba[4] = {bv.x, bv.y, bv.z, bv.w};
#pragma unroll
        for (int n4 = 0; n4 < 2; ++n4) {
          const int key = n4 * 16 + l16;
          if (w < 2) {
            const int e0 = w * 64 + m4 * 16 + quad * 4;
            ushort4 pk;
            pk.x = f2bf(acc[m4][n4][0] + ba[0]);
            pk.y = f2bf(acc[m4][n4][1] + ba[1]);
            pk.z = f2bf(acc[m4][n4][2] + ba[2]);
            pk.w = f2bf(acc[m4][n4][3] + ba[3]);
            *(ushort4*)&sK[key * 136 + e0] = pk;
          } else {
            const int e0 = (w - 2) * 64 + m4 * 16 + quad * 4;
#pragma unroll
            for (int r = 0; r < 4; ++r)
              sVT[(e0 + r) * 40 + key] = f2bf(acc[m4][n4][r] + ba[r]);
          }
        }
      }
    }
    __syncthreads();

    // ---------------- scores + mask + online softmax + P (wave-private, no barriers)
#pragma unroll
    for (int mt = 0; mt < 2; ++mt) {
      const bf16x8 aq = *(const bf16x8*)&sQ[(mt * 16 + l16) * 136 + el + quad * 8];
      floatx4 sc[2];
#pragma unroll
      for (int n4 = 0; n4 < 2; ++n4) {
        const bf16x8 bk = *(const bf16x8*)&sK[(n4 * 16 + l16) * 136 + el + quad * 8];
        sc[n4] = __builtin_amdgcn_mfma_f32_16x16x32_bf16(aq, bk, fzero, 0, 0, 0);
      }
      float rowm[4] = {-1e30f, -1e30f, -1e30f, -1e30f};
#pragma unroll
      for (int n4 = 0; n4 < 2; ++n4) {
        const int kabs = t0 + n4 * 16 + l16;
        const unsigned ki = ((unsigned)kabs * 110377u) >> 21;  // kabs/19, kabs<=383
        const unsigned kj = (unsigned)kabs - ki * 19u;
#pragma unroll
        for (int r = 0; r < 4; ++r) {
          const unsigned j = (unsigned)(mt * 16 + quad * 4 + r);
          const bool ok = (kabs < NPOS) &&
                          (ki == (unsigned)c || kj == (unsigned)c || ki == j || kj == j);
          const float v = ok ? sc[n4][r] : -1e30f;
          sc[n4][r] = v;
          rowm[r] = fmaxf(rowm[r], v);
        }
      }
#pragma unroll
      for (int r = 0; r < 4; ++r) {
#pragma unroll
        for (int m = 1; m < 16; m <<= 1) rowm[r] = fmaxf(rowm[r], __shfl_xor(rowm[r], m));
      }
      float alpha[4];
#pragma unroll
      for (int r = 0; r < 4; ++r) {
        const float mnew = fmaxf(m_run[mt][r], rowm[r]);
        alpha[r] = __expf(m_run[mt][r] - mnew);
        m_run[mt][r] = mnew;
        l_run[mt][r] *= alpha[r];
      }
      float rs[4] = {0.f, 0.f, 0.f, 0.f};
#pragma unroll
      for (int n4 = 0; n4 < 2; ++n4) {
#pragma unroll
        for (int r = 0; r < 4; ++r) {
          const float p = __expf(sc[n4][r] - m_run[mt][r]);
          rs[r] += p;
          sP[(mt * 16 + quad * 4 + r) * 40 + n4 * 16 + l16] = f2bf(p);
        }
      }
#pragma unroll
      for (int r = 0; r < 4; ++r) {
#pragma unroll
        for (int m = 1; m < 16; m <<= 1) rs[r] += __shfl_xor(rs[r], m);
        l_run[mt][r] += rs[r];
      }
#pragma unroll
      for (int nt2 = 0; nt2 < 2; ++nt2)
#pragma unroll
        for (int r = 0; r < 4; ++r) o_acc[mt][nt2][r] *= alpha[r];
    }

    // ---------------- PV: O += P @ V (wave-private P; sVT read covered by barriers)
    {
      bf16x8 ap[2], bv8[2];
#pragma unroll
      for (int mt = 0; mt < 2; ++mt)
        ap[mt] = *(const bf16x8*)&sP[(mt * 16 + l16) * 40 + quad * 8];
#pragma unroll
      for (int nt2 = 0; nt2 < 2; ++nt2)
        bv8[nt2] = *(const bf16x8*)&sVT[(el + nt2 * 16 + l16) * 40 + quad * 8];
#pragma unroll
      for (int mt = 0; mt < 2; ++mt)
#pragma unroll
        for (int nt2 = 0; nt2 < 2; ++nt2)
          o_acc[mt][nt2] =
              __builtin_amdgcn_mfma_f32_16x16x32_bf16(ap[mt], bv8[nt2], o_acc[mt][nt2], 0, 0, 0);
    }
  }  // tile loop

  // ---------------- AO (f32) -> d_out staging, rows j<19 only
#pragma unroll
  for (int mt = 0; mt < 2; ++mt) {
    float invl[4];
#pragma unroll
    for (int r = 0; r < 4; ++r) invl[r] = 1.f / l_run[mt][r];
#pragma unroll
    for (int nt2 = 0; nt2 < 2; ++nt2) {
#pragma unroll
      for (int r = 0; r < 4; ++r) {
        const int j = mt * 16 + quad * 4 + r;
        if (j < CC) {
          out[(b * NPOS + c * CC + j) * DIM + g * 128 + el + nt2 * 16 + l16] =
              o_acc[mt][nt2][r] * invl[r];
        }
      }
    }
  }
}

// Epilogue: per (c,b): proj = AO @ w_out^T + b_out; out = proj @ w_fuse^T + b_fuse + x.
// Reads AO (f32) from d_out rows c*19..c*19+18, then overwrites those rows.
__launch_bounds__(256, 2)
__global__ void epi_kernel(const float* __restrict__ xf,
                           const float* __restrict__ b_out,
                           const float* __restrict__ b_fuse,
                           const unsigned short* __restrict__ wobf,
                           const unsigned short* __restrict__ wfbf,
                           float* __restrict__ out) {
  const int bid = blockIdx.x;
  const int xcd = bid & 7;
  const int slot = bid >> 3;
  int c, b;
  if (slot < 64) {
    c = ((slot >> 5) << 3) + xcd;
    b = slot & 31;
  } else {
    const int widx = ((slot - 64) << 3) + xcd;
    c = 16 + (widx >> 5);
    b = widx & 31;
  }

  const int tid = threadIdx.x;
  const int w = tid >> 6;
  const int lane = tid & 63;
  const int quad = lane >> 4;
  const int l16 = lane & 15;

  __shared__ unsigned short sAO[32 * 264];
  __shared__ unsigned short sT[32 * 264];
  const floatx4 fzero = {0.f, 0.f, 0.f, 0.f};

  // load AO f32 -> bf16 LDS, zero rows >= 19
#pragma unroll
  for (int it = 0; it < 8; ++it) {
    const int cc2 = tid + it * 256;
    const int row = cc2 >> 6;
    const int col = (cc2 & 63) * 4;
    float4 v = make_float4(0.f, 0.f, 0.f, 0.f);
    if (row < CC) v = *(const float4*)&out[(b * NPOS + c * CC + row) * DIM + col];
    ushort4 o;
    o.x = f2bf(v.x); o.y = f2bf(v.y); o.z = f2bf(v.z); o.w = f2bf(v.w);
    *(ushort4*)&sAO[row * 264 + col] = o;
  }
  __syncthreads();

  // GEMM1: proj = AO @ w_out^T + b_out -> sT
#pragma unroll
  for (int mt = 0; mt < 2; ++mt) {
    bf16x8 a8[8];
#pragma unroll
    for (int k = 0; k < 8; ++k)
      a8[k] = *(const bf16x8*)&sAO[(mt * 16 + l16) * 264 + k * 32 + quad * 8];
#pragma unroll
    for (int nt = 0; nt < 4; ++nt) {
      const int e0 = w * 64 + nt * 16;
      floatx4 acc = fzero;
#pragma unroll
      for (int k = 0; k < 8; ++k) {
        bf16x8 b8 = *(const bf16x8*)&wobf[(c * 256 + e0 + l16) * DIM + k * 32 + quad * 8];
        acc = __builtin_amdgcn_mfma_f32_16x16x32_bf16(a8[k], b8, acc, 0, 0, 0);
      }
      const float bias = b_out[c * 256 + e0 + l16];
#pragma unroll
      for (int r = 0; r < 4; ++r)
        sT[(mt * 16 + quad * 4 + r) * 264 + e0 + l16] = f2bf(acc[r] + bias);
    }
  }
  __syncthreads();

  // GEMM2: out = proj @ w_fuse^T + b_fuse + x
#pragma unroll
  for (int mt = 0; mt < 2; ++mt) {
    bf16x8 a8[8];
#pragma unroll
    for (int k = 0; k < 8; ++k)
      a8[k] = *(const bf16x8*)&sT[(mt * 16 + l16) * 264 + k * 32 + quad * 8];
#pragma unroll
    for (int nt = 0; nt < 4; ++nt) {
      const int e0 = w * 64 + nt * 16;
      floatx4 acc = fzero;
#pragma unroll
      for (int k = 0; k < 8; ++k) {
        bf16x8 b8 = *(const bf16x8*)&wfbf[(e0 + l16) * DIM + k * 32 + quad * 8];
        acc = __builtin_amdgcn_mfma_f32_16x16x32_bf16(a8[k], b8, acc, 0, 0, 0);
      }
      const float bfu = b_fuse[e0 + l16];
#pragma unroll
      for (int r = 0; r < 4; ++r) {
        const int row = mt * 16 + quad * 4 + r;
        if (row < CC) {
          const int gp = (b * NPOS + c * CC + row) * DIM + e0 + l16;
          out[gp] = acc[r] + bfu + xf[gp];
        }
      }
    }
  }
}

extern "C" void kernel_launch(void* const* d_in, const int* in_sizes, int n_in,
                              void* d_out, int out_size, void* d_ws, size_t ws_size,
                              hipStream_t stream) {
  const float* x      = (const float*)d_in[0];
  const float* w_in   = (const float*)d_in[1];
  const float* b_in   = (const float*)d_in[2];
  const float* w_out  = (const float*)d_in[3];
  const float* b_out  = (const float*)d_in[4];
  const float* w_fuse = (const float*)d_in[5];
  const float* b_fuse = (const float*)d_in[6];
  float* out = (float*)d_out;

  if (ws_size < (size_t)16384000) return;  // 16.38 MB bf16 scratch (validated bound)

  unsigned short* ws = (unsigned short*)d_ws;
  unsigned short* x_bf  = ws;              // 32*384*256   = 3,145,728
  unsigned short* wi_bf = ws + 3145728;    // 19*768*256   = 3,735,552
  unsigned short* wo_bf = ws + 6881280;    // 19*256*256   = 1,245,184
  unsigned short* wf_bf = ws + 8126464;    // 256*256      = 65,536

  conv_all_kernel<<<8000, 256, 0, stream>>>(x, w_in, w_out, w_fuse, ws);
  attn_kernel<<<1216, 256, 0, stream>>>(b_in, x_bf, wi_bf, out);
  epi_kernel<<<608, 256, 0, stream>>>(x, b_out, b_fuse, wo_bf, wf_bf, out);
}

// Round 5
// 367.597 us; speedup vs baseline: 1.6066x; 1.6066x over previous
//
#include <hip/hip_runtime.h>

#define CC 19
#define NPOS 361
#define NPAD 384
#define DIM 256
#define TKEY 32
#define NTILES 12

// LDS layout (bytes), double-buffered pipeline, 1 barrier/tile:
//   sQ     : 32 x 264 bf16              = 16896   [0)
//   bufx   : 2 x 32 x 264 bf16          = 33792   [16896)
//   sK     : 2 x 32 x 264 bf16          = 33792   [50688)
//   sVT    : 2 x 256 x 40 bf16          = 40960   [84480)
//   sP     : 8 waves x 32 x 40 bf16     = 20480   [125440)
// total = 145920 (<=160KB; 1 block/CU is structural anyway at ~164 regs)
#define LDS_BYTES 145920

using bf16x8 = __attribute__((ext_vector_type(8))) short;
using floatx4 = __attribute__((ext_vector_type(4))) float;

__device__ __forceinline__ unsigned short f2bf(float f) {
  unsigned u = __builtin_bit_cast(unsigned, f);
  u += 0x7fffu + ((u >> 16) & 1u);
  return (unsigned short)(u >> 16);
}

// fused conversion: x (zero-padded 361->384 rows) + all weights, f32 -> bf16
__global__ void conv_all_kernel(const float* __restrict__ x,
                                const float* __restrict__ w_in,
                                const float* __restrict__ w_out,
                                const float* __restrict__ w_fuse,
                                unsigned short* __restrict__ ws) {
  const int j = blockIdx.x * 256 + threadIdx.x;
  float4 v = make_float4(0.f, 0.f, 0.f, 0.f);
  unsigned short* dst;
  if (j < 786432) {
    const int row = j >> 6;
    const int off = (j & 63) << 2;
    const int b = row / NPAD;
    const int r = row - b * NPAD;
    if (r < NPOS) v = *(const float4*)&x[(b * NPOS + r) * DIM + off];
    dst = &ws[row * DIM + off];
  } else if (j < 1720320) {
    const int k = j - 786432;
    v = *(const float4*)&w_in[k << 2];
    dst = &ws[3145728 + (k << 2)];
  } else if (j < 2031616) {
    const int k = j - 1720320;
    v = *(const float4*)&w_out[k << 2];
    dst = &ws[6881280 + (k << 2)];
  } else {
    const int k = j - 2031616;
    v = *(const float4*)&w_fuse[k << 2];
    dst = &ws[8126464 + (k << 2)];
  }
  ushort4 o;
  o.x = f2bf(v.x); o.y = f2bf(v.y); o.z = f2bf(v.z); o.w = f2bf(v.w);
  *(ushort4*)dst = o;
}

// launch_bounds (512,2): VGPR cap 256 -> natural ~128+AGPR, NO spills.
// (R2/R4 lesson: forcing below ~164 unified regs spills and costs 3x.)
__launch_bounds__(512, 2)
__global__ void cgca_kernel(const float* __restrict__ xf,
                            const float* __restrict__ b_in,
                            const float* __restrict__ b_out,
                            const float* __restrict__ b_fuse,
                            const unsigned short* __restrict__ xbf,
                            const unsigned short* __restrict__ wibf,
                            const unsigned short* __restrict__ wobf,
                            const unsigned short* __restrict__ wfbf,
                            float* __restrict__ out) {
  // XCD-aware swizzle: same channel's 32 batches contiguous on one XCD.
  const int bid = blockIdx.x;
  const int xcd = bid & 7;
  const int slot = bid >> 3;
  int c, b;
  if (slot < 64) {
    c = ((slot >> 5) << 3) + xcd;   // channels 0..15
    b = slot & 31;
  } else {
    const int widx = ((slot - 64) << 3) + xcd;  // 0..95
    c = 16 + (widx >> 5);           // channels 16..18
    b = widx & 31;
  }

  const int tid = threadIdx.x;
  const int w = tid >> 6;        // wave 0..7 == head index
  const int lane = tid & 63;
  const int quad = lane >> 4;
  const int l16 = lane & 15;

  extern __shared__ char smem[];
  unsigned short* sQ    = (unsigned short*)(smem);
  unsigned short* bufx0 = (unsigned short*)(smem + 16896);
  unsigned short* bufx1 = (unsigned short*)(smem + 16896 + 16896);
  unsigned short* sK0   = (unsigned short*)(smem + 50688);
  unsigned short* sK1   = (unsigned short*)(smem + 50688 + 16896);
  unsigned short* sVT0  = (unsigned short*)(smem + 84480);
  unsigned short* sVT1  = (unsigned short*)(smem + 84480 + 20480);
  unsigned short* sP    = (unsigned short*)(smem + 125440) + w * 1280;  // 32x40 wave-private

  const float scale = 0.17677669529663687f;  // 1/sqrt(32)
  const floatx4 fzero = {0.f, 0.f, 0.f, 0.f};

  // ---------------- Phase 1: Q = xq @ wq^T + bq (scaled) -> sQ bf16 [32][264]
  {
    const int eh0 = w * 32;
#pragma unroll
    for (int mt = 0; mt < 2; ++mt) {
      const int xrow = b * NPAD + c * CC + mt * 16 + l16;  // zero-padded rows
      bf16x8 a8[8];
#pragma unroll
      for (int k = 0; k < 8; ++k)
        a8[k] = *(const bf16x8*)&xbf[xrow * DIM + k * 32 + quad * 8];
#pragma unroll
      for (int nt2 = 0; nt2 < 2; ++nt2) {
        const int e0 = eh0 + nt2 * 16;
        floatx4 acc = fzero;
#pragma unroll
        for (int k = 0; k < 8; ++k) {
          bf16x8 b8 = *(const bf16x8*)&wibf[(c * 768 + e0 + l16) * DIM + k * 32 + quad * 8];
          acc = __builtin_amdgcn_mfma_f32_16x16x32_bf16(a8[k], b8, acc, 0, 0, 0);
        }
        const float bias = b_in[c * 768 + e0 + l16];
#pragma unroll
        for (int r = 0; r < 4; ++r)
          sQ[(mt * 16 + quad * 4 + r) * 264 + e0 + l16] = f2bf((acc[r] + bias) * scale);
      }
    }
  }

  // stage x tile 0 -> bufx0
#pragma unroll
  for (int it = 0; it < 2; ++it) {
    const int cc2 = tid + it * 512;
    const int row = cc2 >> 5;
    const int col = (cc2 & 31) * 8;
    *(bf16x8*)&bufx0[row * 264 + col] = *(const bf16x8*)&xbf[(b * NPAD + row) * DIM + col];
  }

  floatx4 o_acc[2][2];
  float m_run[2][4], l_run[2][4];
#pragma unroll
  for (int mt = 0; mt < 2; ++mt) {
#pragma unroll
    for (int nt2 = 0; nt2 < 2; ++nt2) o_acc[mt][nt2] = fzero;
#pragma unroll
    for (int r = 0; r < 4; ++r) { m_run[mt][r] = -1e30f; l_run[mt][r] = 0.f; }
  }
  const int eh = w * 32;

  __syncthreads();  // Q in sQ, x(0) staged

  for (int t = 0; t < NTILES; ++t) {
    const int t0 = t * TKEY;
    unsigned short* bx  = (t & 1) ? bufx1 : bufx0;
    unsigned short* bxn = (t & 1) ? bufx0 : bufx1;
    unsigned short* sK  = (t & 1) ? sK1 : sK0;
    unsigned short* sVT = (t & 1) ? sVT1 : sVT0;

    // stage x(t+1) -> other buffer (no barrier needed: nobody reads it until
    // after the next barrier; nobody else writes it)
    if (t + 1 < NTILES) {
#pragma unroll
      for (int it = 0; it < 2; ++it) {
        const int cc2 = tid + it * 512;
        const int row = cc2 >> 5;
        const int col = (cc2 & 31) * 8;
        *(bf16x8*)&bxn[row * 264 + col] =
            *(const bf16x8*)&xbf[(b * NPAD + t0 + TKEY + row) * DIM + col];
      }
    }

    // ---------------- KV^T projection: rows e' = w*64..w*64+63 of [wk;wv]
    {
      floatx4 acc[4][2];
#pragma unroll
      for (int m4 = 0; m4 < 4; ++m4)
#pragma unroll
        for (int n4 = 0; n4 < 2; ++n4) acc[m4][n4] = fzero;

      const int wrow0 = c * 768 + 256 + w * 64;
      bf16x8 abuf[2][4];
#pragma unroll
      for (int m4 = 0; m4 < 4; ++m4)
        abuf[0][m4] = *(const bf16x8*)&wibf[(wrow0 + m4 * 16 + l16) * DIM + quad * 8];
#pragma unroll
      for (int k = 0; k < 8; ++k) {
        if (k < 7) {
#pragma unroll
          for (int m4 = 0; m4 < 4; ++m4)
            abuf[(k + 1) & 1][m4] =
                *(const bf16x8*)&wibf[(wrow0 + m4 * 16 + l16) * DIM + (k + 1) * 32 + quad * 8];
        }
        bf16x8 bfr[2];
#pragma unroll
        for (int n4 = 0; n4 < 2; ++n4)
          bfr[n4] = *(const bf16x8*)&bx[(n4 * 16 + l16) * 264 + k * 32 + quad * 8];
#pragma unroll
        for (int m4 = 0; m4 < 4; ++m4)
#pragma unroll
          for (int n4 = 0; n4 < 2; ++n4)
            acc[m4][n4] = __builtin_amdgcn_mfma_f32_16x16x32_bf16(abuf[k & 1][m4], bfr[n4],
                                                                  acc[m4][n4], 0, 0, 0);
      }
      // epilogue: +bias, cvt bf16, store K [key][e] / V^T [e][key]
#pragma unroll
      for (int m4 = 0; m4 < 4; ++m4) {
        const float4 bv = *(const float4*)&b_in[c * 768 + 256 + w * 64 + m4 * 16 + quad * 4];
        const float ba[4] = {bv.x, bv.y, bv.z, bv.w};
#pragma unroll
        for (int n4 = 0; n4 < 2; ++n4) {
          const int key = n4 * 16 + l16;
          if (w < 4) {
            const int e0 = w * 64 + m4 * 16 + quad * 4;
            ushort4 pk;
            pk.x = f2bf(acc[m4][n4][0] + ba[0]);
            pk.y = f2bf(acc[m4][n4][1] + ba[1]);
            pk.z = f2bf(acc[m4][n4][2] + ba[2]);
            pk.w = f2bf(acc[m4][n4][3] + ba[3]);
            *(ushort4*)&sK[key * 264 + e0] = pk;
          } else {
            const int e0 = (w - 4) * 64 + m4 * 16 + quad * 4;
#pragma unroll
            for (int r = 0; r < 4; ++r)
              sVT[(e0 + r) * 40 + key] = f2bf(acc[m4][n4][r] + ba[r]);
          }
        }
      }
    }
    __syncthreads();  // the ONE barrier: kv[t] ready; fast waves may run ahead
                      // into proj(t+1) (other buffer) while slow waves softmax

    // ---------------- scores + mask + online softmax + P (wave-private)
#pragma unroll
    for (int mt = 0; mt < 2; ++mt) {
      const bf16x8 aq = *(const bf16x8*)&sQ[(mt * 16 + l16) * 264 + eh + quad * 8];
      floatx4 sc[2];
#pragma unroll
      for (int n4 = 0; n4 < 2; ++n4) {
        const bf16x8 bk = *(const bf16x8*)&sK[(n4 * 16 + l16) * 264 + eh + quad * 8];
        sc[n4] = __builtin_amdgcn_mfma_f32_16x16x32_bf16(aq, bk, fzero, 0, 0, 0);
      }
      float rowm[4] = {-1e30f, -1e30f, -1e30f, -1e30f};
#pragma unroll
      for (int n4 = 0; n4 < 2; ++n4) {
        const int kabs = t0 + n4 * 16 + l16;
        const unsigned ki = ((unsigned)kabs * 110377u) >> 21;  // kabs/19, kabs<=383
        const unsigned kj = (unsigned)kabs - ki * 19u;
#pragma unroll
        for (int r = 0; r < 4; ++r) {
          const unsigned j = (unsigned)(mt * 16 + quad * 4 + r);
          const bool ok = (kabs < NPOS) &&
                          (ki == (unsigned)c || kj == (unsigned)c || ki == j || kj == j);
          const float v = ok ? sc[n4][r] : -1e30f;
          sc[n4][r] = v;
          rowm[r] = fmaxf(rowm[r], v);
        }
      }
#pragma unroll
      for (int r = 0; r < 4; ++r) {
#pragma unroll
        for (int m = 1; m < 16; m <<= 1) rowm[r] = fmaxf(rowm[r], __shfl_xor(rowm[r], m));
      }
      float alpha[4];
#pragma unroll
      for (int r = 0; r < 4; ++r) {
        const float mnew = fmaxf(m_run[mt][r], rowm[r]);
        alpha[r] = __expf(m_run[mt][r] - mnew);
        m_run[mt][r] = mnew;
        l_run[mt][r] *= alpha[r];
      }
      float rs[4] = {0.f, 0.f, 0.f, 0.f};
#pragma unroll
      for (int n4 = 0; n4 < 2; ++n4) {
#pragma unroll
        for (int r = 0; r < 4; ++r) {
          const float p = __expf(sc[n4][r] - m_run[mt][r]);
          rs[r] += p;
          sP[(mt * 16 + quad * 4 + r) * 40 + n4 * 16 + l16] = f2bf(p);
        }
      }
#pragma unroll
      for (int r = 0; r < 4; ++r) {
#pragma unroll
        for (int m = 1; m < 16; m <<= 1) rs[r] += __shfl_xor(rs[r], m);
        l_run[mt][r] += rs[r];
      }
#pragma unroll
      for (int nt2 = 0; nt2 < 2; ++nt2)
#pragma unroll
        for (int r = 0; r < 4; ++r) o_acc[mt][nt2][r] *= alpha[r];
    }

    // ---------------- PV: O += P @ V (wave-private P, same-buffer V)
    {
      bf16x8 ap[2], bv8[2];
#pragma unroll
      for (int mt = 0; mt < 2; ++mt)
        ap[mt] = *(const bf16x8*)&sP[(mt * 16 + l16) * 40 + quad * 8];
#pragma unroll
      for (int nt2 = 0; nt2 < 2; ++nt2)
        bv8[nt2] = *(const bf16x8*)&sVT[(eh + nt2 * 16 + l16) * 40 + quad * 8];
#pragma unroll
      for (int mt = 0; mt < 2; ++mt)
#pragma unroll
        for (int nt2 = 0; nt2 < 2; ++nt2)
          o_acc[mt][nt2] =
              __builtin_amdgcn_mfma_f32_16x16x32_bf16(ap[mt], bv8[nt2], o_acc[mt][nt2], 0, 0, 0);
    }
  }  // tile loop

  // ---------------- finalize O -> bufx0 (as attn-out, bf16, wave-private cols)
#pragma unroll
  for (int mt = 0; mt < 2; ++mt) {
    float invl[4];
#pragma unroll
    for (int r = 0; r < 4; ++r) invl[r] = 1.f / l_run[mt][r];
#pragma unroll
    for (int nt2 = 0; nt2 < 2; ++nt2)
#pragma unroll
      for (int r = 0; r < 4; ++r)
        bufx0[(mt * 16 + quad * 4 + r) * 264 + eh + nt2 * 16 + l16] =
            f2bf(o_acc[mt][nt2][r] * invl[r]);
  }
  __syncthreads();

  // ---------------- GEMM1: proj = AO @ w_out^T + b_out -> sK0 (bf16)
#pragma unroll
  for (int mt = 0; mt < 2; ++mt) {
    bf16x8 a8[8];
#pragma unroll
    for (int k = 0; k < 8; ++k)
      a8[k] = *(const bf16x8*)&bufx0[(mt * 16 + l16) * 264 + k * 32 + quad * 8];
#pragma unroll
    for (int nt2 = 0; nt2 < 2; ++nt2) {
      const int e0 = w * 32 + nt2 * 16;
      floatx4 acc = fzero;
#pragma unroll
      for (int k = 0; k < 8; ++k) {
        bf16x8 b8 = *(const bf16x8*)&wobf[(c * 256 + e0 + l16) * DIM + k * 32 + quad * 8];
        acc = __builtin_amdgcn_mfma_f32_16x16x32_bf16(a8[k], b8, acc, 0, 0, 0);
      }
      const float bias = b_out[c * 256 + e0 + l16];
#pragma unroll
      for (int r = 0; r < 4; ++r)
        sK0[(mt * 16 + quad * 4 + r) * 264 + e0 + l16] = f2bf(acc[r] + bias);
    }
  }
  __syncthreads();

  // ---------------- GEMM2: out = proj @ w_fuse^T + b_fuse + x
#pragma unroll
  for (int mt = 0; mt < 2; ++mt) {
    bf16x8 a8[8];
#pragma unroll
    for (int k = 0; k < 8; ++k)
      a8[k] = *(const bf16x8*)&sK0[(mt * 16 + l16) * 264 + k * 32 + quad * 8];
#pragma unroll
    for (int nt2 = 0; nt2 < 2; ++nt2) {
      const int e0 = w * 32 + nt2 * 16;
      floatx4 acc = fzero;
#pragma unroll
      for (int k = 0; k < 8; ++k) {
        bf16x8 b8 = *(const bf16x8*)&wfbf[(e0 + l16) * DIM + k * 32 + quad * 8];
        acc = __builtin_amdgcn_mfma_f32_16x16x32_bf16(a8[k], b8, acc, 0, 0, 0);
      }
      const float bfu = b_fuse[e0 + l16];
#pragma unroll
      for (int r = 0; r < 4; ++r) {
        const int row = mt * 16 + quad * 4 + r;
        if (row < CC) {
          const int gp = (b * NPOS + c * CC + row) * DIM + e0 + l16;
          out[gp] = acc[r] + bfu + xf[gp];
        }
      }
    }
  }
}

extern "C" void kernel_launch(void* const* d_in, const int* in_sizes, int n_in,
                              void* d_out, int out_size, void* d_ws, size_t ws_size,
                              hipStream_t stream) {
  const float* x      = (const float*)d_in[0];
  const float* w_in   = (const float*)d_in[1];
  const float* b_in   = (const float*)d_in[2];
  const float* w_out  = (const float*)d_in[3];
  const float* b_out  = (const float*)d_in[4];
  const float* w_fuse = (const float*)d_in[5];
  const float* b_fuse = (const float*)d_in[6];
  float* out = (float*)d_out;

  if (ws_size < (size_t)16384000) return;  // 16.38 MB bf16 scratch (validated bound)

  unsigned short* ws = (unsigned short*)d_ws;
  unsigned short* x_bf  = ws;              // 32*384*256   = 3,145,728
  unsigned short* wi_bf = ws + 3145728;    // 19*768*256   = 3,735,552
  unsigned short* wo_bf = ws + 6881280;    // 19*256*256   = 1,245,184
  unsigned short* wf_bf = ws + 8126464;    // 256*256      = 65,536

  conv_all_kernel<<<8000, 256, 0, stream>>>(x, w_in, w_out, w_fuse, ws);

  (void)hipFuncSetAttribute((const void*)cgca_kernel,
                            hipFuncAttributeMaxDynamicSharedMemorySize, LDS_BYTES);
  cgca_kernel<<<608, 512, LDS_BYTES, stream>>>(x, b_in, b_out, b_fuse, x_bf, wi_bf,
                                               wo_bf, wf_bf, out);
}

// Round 6
// 362.425 us; speedup vs baseline: 1.6295x; 1.0143x over previous
//
#include <hip/hip_runtime.h>

#define CC 19
#define NPOS 361
#define NPAD 384
#define DIM 256
#define TKEY 32
#define NTILES 12

// LDS layout (bytes), double-buffered pipeline, 1 barrier/tile:
//   sQ     : 32 x 264 bf16              = 16896   [0)
//   bufx   : 2 x 32 x 264 bf16          = 33792   [16896)
//   sK     : 2 x 32 x 264 bf16          = 33792   [50688)
//   sVT    : 2 x 256 x 40 bf16          = 40960   [84480)
//   sP     : 8 waves x 32 x 40 bf16     = 20480   [125440)
// total = 145920 (<=160KB; 1 block/CU is structural anyway at ~236 regs)
#define LDS_BYTES 145920

using bf16x8 = __attribute__((ext_vector_type(8))) short;
using floatx4 = __attribute__((ext_vector_type(4))) float;

__device__ __forceinline__ unsigned short f2bf(float f) {
  unsigned u = __builtin_bit_cast(unsigned, f);
  u += 0x7fffu + ((u >> 16) & 1u);
  return (unsigned short)(u >> 16);
}

// fused conversion: x (zero-padded 361->384 rows) + all weights, f32 -> bf16
__global__ void conv_all_kernel(const float* __restrict__ x,
                                const float* __restrict__ w_in,
                                const float* __restrict__ w_out,
                                const float* __restrict__ w_fuse,
                                unsigned short* __restrict__ ws) {
  const int j = blockIdx.x * 256 + threadIdx.x;
  float4 v = make_float4(0.f, 0.f, 0.f, 0.f);
  unsigned short* dst;
  if (j < 786432) {
    const int row = j >> 6;
    const int off = (j & 63) << 2;
    const int b = row / NPAD;
    const int r = row - b * NPAD;
    if (r < NPOS) v = *(const float4*)&x[(b * NPOS + r) * DIM + off];
    dst = &ws[row * DIM + off];
  } else if (j < 1720320) {
    const int k = j - 786432;
    v = *(const float4*)&w_in[k << 2];
    dst = &ws[3145728 + (k << 2)];
  } else if (j < 2031616) {
    const int k = j - 1720320;
    v = *(const float4*)&w_out[k << 2];
    dst = &ws[6881280 + (k << 2)];
  } else {
    const int k = j - 2031616;
    v = *(const float4*)&w_fuse[k << 2];
    dst = &ws[8126464 + (k << 2)];
  }
  ushort4 o;
  o.x = f2bf(v.x); o.y = f2bf(v.y); o.z = f2bf(v.z); o.w = f2bf(v.w);
  *(ushort4*)dst = o;
}

// launch_bounds (512,2): VGPR cap 256 -> weight-resident regs fit, NO spills.
// (R2/R4 lesson: forcing below the natural liveset spills and costs 3x.)
__launch_bounds__(512, 2)
__global__ void cgca_kernel(const float* __restrict__ xf,
                            const float* __restrict__ b_in,
                            const float* __restrict__ b_out,
                            const float* __restrict__ b_fuse,
                            const unsigned short* __restrict__ xbf,
                            const unsigned short* __restrict__ wibf,
                            const unsigned short* __restrict__ wobf,
                            const unsigned short* __restrict__ wfbf,
                            float* __restrict__ out) {
  // XCD-aware swizzle: same channel's 32 batches contiguous on one XCD.
  const int bid = blockIdx.x;
  const int xcd = bid & 7;
  const int slot = bid >> 3;
  int c, b;
  if (slot < 64) {
    c = ((slot >> 5) << 3) + xcd;   // channels 0..15
    b = slot & 31;
  } else {
    const int widx = ((slot - 64) << 3) + xcd;  // 0..95
    c = 16 + (widx >> 5);           // channels 16..18
    b = widx & 31;
  }

  const int tid = threadIdx.x;
  const int w = tid >> 6;        // wave 0..7 == head index
  const int lane = tid & 63;
  const int quad = lane >> 4;
  const int l16 = lane & 15;

  extern __shared__ char smem[];
  unsigned short* sQ    = (unsigned short*)(smem);
  unsigned short* bufx0 = (unsigned short*)(smem + 16896);
  unsigned short* bufx1 = (unsigned short*)(smem + 16896 + 16896);
  unsigned short* sK0   = (unsigned short*)(smem + 50688);
  unsigned short* sK1   = (unsigned short*)(smem + 50688 + 16896);
  unsigned short* sVT0  = (unsigned short*)(smem + 84480);
  unsigned short* sVT1  = (unsigned short*)(smem + 84480 + 20480);
  unsigned short* sP    = (unsigned short*)(smem + 125440) + w * 1280;  // 32x40 wave-private

  const float scale = 0.17677669529663687f;  // 1/sqrt(32)
  const floatx4 fzero = {0.f, 0.f, 0.f, 0.f};

  // ---------------- Phase 1: Q = xq @ wq^T + bq (scaled) -> sQ bf16 [32][264]
  {
    const int eh0 = w * 32;
#pragma unroll
    for (int mt = 0; mt < 2; ++mt) {
      const int xrow = b * NPAD + c * CC + mt * 16 + l16;  // zero-padded rows
      bf16x8 a8[8];
#pragma unroll
      for (int k = 0; k < 8; ++k)
        a8[k] = *(const bf16x8*)&xbf[xrow * DIM + k * 32 + quad * 8];
#pragma unroll
      for (int nt2 = 0; nt2 < 2; ++nt2) {
        const int e0 = eh0 + nt2 * 16;
        floatx4 acc = fzero;
#pragma unroll
        for (int k = 0; k < 8; ++k) {
          bf16x8 b8 = *(const bf16x8*)&wibf[(c * 768 + e0 + l16) * DIM + k * 32 + quad * 8];
          acc = __builtin_amdgcn_mfma_f32_16x16x32_bf16(a8[k], b8, acc, 0, 0, 0);
        }
        const float bias = b_in[c * 768 + e0 + l16];
#pragma unroll
        for (int r = 0; r < 4; ++r)
          sQ[(mt * 16 + quad * 4 + r) * 264 + e0 + l16] = f2bf((acc[r] + bias) * scale);
      }
    }
  }

  // ---------------- KV weight slab -> registers, ONCE (128 VGPRs/wave).
  // Loop-invariant across all 12 tiles; LICM can't hoist this much, so we do.
  const int wrow0 = c * 768 + 256 + w * 64;
  bf16x8 wreg[4][8];
#pragma unroll
  for (int m4 = 0; m4 < 4; ++m4)
#pragma unroll
    for (int k = 0; k < 8; ++k)
      wreg[m4][k] = *(const bf16x8*)&wibf[(wrow0 + m4 * 16 + l16) * DIM + k * 32 + quad * 8];

  // stage x tile 0 -> bufx0
#pragma unroll
  for (int it = 0; it < 2; ++it) {
    const int cc2 = tid + it * 512;
    const int row = cc2 >> 5;
    const int col = (cc2 & 31) * 8;
    *(bf16x8*)&bufx0[row * 264 + col] = *(const bf16x8*)&xbf[(b * NPAD + row) * DIM + col];
  }

  floatx4 o_acc[2][2];
  float m_run[2][4], l_run[2][4];
#pragma unroll
  for (int mt = 0; mt < 2; ++mt) {
#pragma unroll
    for (int nt2 = 0; nt2 < 2; ++nt2) o_acc[mt][nt2] = fzero;
#pragma unroll
    for (int r = 0; r < 4; ++r) { m_run[mt][r] = -1e30f; l_run[mt][r] = 0.f; }
  }
  const int eh = w * 32;

  __syncthreads();  // Q in sQ, x(0) staged

  for (int t = 0; t < NTILES; ++t) {
    const int t0 = t * TKEY;
    unsigned short* bx  = (t & 1) ? bufx1 : bufx0;
    unsigned short* bxn = (t & 1) ? bufx0 : bufx1;
    unsigned short* sK  = (t & 1) ? sK1 : sK0;
    unsigned short* sVT = (t & 1) ? sVT1 : sVT0;

    // stage x(t+1) -> other buffer (only global loads in the loop; hidden
    // behind the 64 proj MFMAs below)
    if (t + 1 < NTILES) {
#pragma unroll
      for (int it = 0; it < 2; ++it) {
        const int cc2 = tid + it * 512;
        const int row = cc2 >> 5;
        const int col = (cc2 & 31) * 8;
        *(bf16x8*)&bxn[row * 264 + col] =
            *(const bf16x8*)&xbf[(b * NPAD + t0 + TKEY + row) * DIM + col];
      }
    }

    // ---------------- KV^T projection from register-resident weights
    {
      floatx4 acc[4][2];
#pragma unroll
      for (int m4 = 0; m4 < 4; ++m4)
#pragma unroll
        for (int n4 = 0; n4 < 2; ++n4) acc[m4][n4] = fzero;

#pragma unroll
      for (int k = 0; k < 8; ++k) {
        bf16x8 bfr[2];
#pragma unroll
        for (int n4 = 0; n4 < 2; ++n4)
          bfr[n4] = *(const bf16x8*)&bx[(n4 * 16 + l16) * 264 + k * 32 + quad * 8];
#pragma unroll
        for (int m4 = 0; m4 < 4; ++m4)
#pragma unroll
          for (int n4 = 0; n4 < 2; ++n4)
            acc[m4][n4] = __builtin_amdgcn_mfma_f32_16x16x32_bf16(wreg[m4][k], bfr[n4],
                                                                  acc[m4][n4], 0, 0, 0);
      }
      // epilogue: +bias (loop-invariant loads, LICM hoists), cvt bf16,
      // store K [key][e] / V^T [e][key]
#pragma unroll
      for (int m4 = 0; m4 < 4; ++m4) {
        const float4 bv = *(const float4*)&b_in[wrow0 + m4 * 16 + quad * 4];
        const float ba[4] = {bv.x, bv.y, bv.z, bv.w};
#pragma unroll
        for (int n4 = 0; n4 < 2; ++n4) {
          const int key = n4 * 16 + l16;
          if (w < 4) {
            const int e0 = w * 64 + m4 * 16 + quad * 4;
            ushort4 pk;
            pk.x = f2bf(acc[m4][n4][0] + ba[0]);
            pk.y = f2bf(acc[m4][n4][1] + ba[1]);
            pk.z = f2bf(acc[m4][n4][2] + ba[2]);
            pk.w = f2bf(acc[m4][n4][3] + ba[3]);
            *(ushort4*)&sK[key * 264 + e0] = pk;
          } else {
            const int e0 = (w - 4) * 64 + m4 * 16 + quad * 4;
#pragma unroll
            for (int r = 0; r < 4; ++r)
              sVT[(e0 + r) * 40 + key] = f2bf(acc[m4][n4][r] + ba[r]);
          }
        }
      }
    }
    __syncthreads();  // the ONE barrier: kv[t] ready; fast waves may run ahead
                      // into proj(t+1) (other buffer) while slow waves softmax

    // ---------------- scores + mask + online softmax + P (wave-private)
#pragma unroll
    for (int mt = 0; mt < 2; ++mt) {
      const bf16x8 aq = *(const bf16x8*)&sQ[(mt * 16 + l16) * 264 + eh + quad * 8];
      floatx4 sc[2];
#pragma unroll
      for (int n4 = 0; n4 < 2; ++n4) {
        const bf16x8 bk = *(const bf16x8*)&sK[(n4 * 16 + l16) * 264 + eh + quad * 8];
        sc[n4] = __builtin_amdgcn_mfma_f32_16x16x32_bf16(aq, bk, fzero, 0, 0, 0);
      }
      float rowm[4] = {-1e30f, -1e30f, -1e30f, -1e30f};
#pragma unroll
      for (int n4 = 0; n4 < 2; ++n4) {
        const int kabs = t0 + n4 * 16 + l16;
        const unsigned ki = ((unsigned)kabs * 110377u) >> 21;  // kabs/19, kabs<=383
        const unsigned kj = (unsigned)kabs - ki * 19u;
#pragma unroll
        for (int r = 0; r < 4; ++r) {
          const unsigned j = (unsigned)(mt * 16 + quad * 4 + r);
          const bool ok = (kabs < NPOS) &&
                          (ki == (unsigned)c || kj == (unsigned)c || ki == j || kj == j);
          const float v = ok ? sc[n4][r] : -1e30f;
          sc[n4][r] = v;
          rowm[r] = fmaxf(rowm[r], v);
        }
      }
#pragma unroll
      for (int r = 0; r < 4; ++r) {
#pragma unroll
        for (int m = 1; m < 16; m <<= 1) rowm[r] = fmaxf(rowm[r], __shfl_xor(rowm[r], m));
      }
      float alpha[4];
#pragma unroll
      for (int r = 0; r < 4; ++r) {
        const float mnew = fmaxf(m_run[mt][r], rowm[r]);
        alpha[r] = __expf(m_run[mt][r] - mnew);
        m_run[mt][r] = mnew;
        l_run[mt][r] *= alpha[r];
      }
      float rs[4] = {0.f, 0.f, 0.f, 0.f};
#pragma unroll
      for (int n4 = 0; n4 < 2; ++n4) {
#pragma unroll
        for (int r = 0; r < 4; ++r) {
          const float p = __expf(sc[n4][r] - m_run[mt][r]);
          rs[r] += p;
          sP[(mt * 16 + quad * 4 + r) * 40 + n4 * 16 + l16] = f2bf(p);
        }
      }
#pragma unroll
      for (int r = 0; r < 4; ++r) {
#pragma unroll
        for (int m = 1; m < 16; m <<= 1) rs[r] += __shfl_xor(rs[r], m);
        l_run[mt][r] += rs[r];
      }
#pragma unroll
      for (int nt2 = 0; nt2 < 2; ++nt2)
#pragma unroll
        for (int r = 0; r < 4; ++r) o_acc[mt][nt2][r] *= alpha[r];
    }

    // ---------------- PV: O += P @ V (wave-private P, same-buffer V)
    {
      bf16x8 ap[2], bv8[2];
#pragma unroll
      for (int mt = 0; mt < 2; ++mt)
        ap[mt] = *(const bf16x8*)&sP[(mt * 16 + l16) * 40 + quad * 8];
#pragma unroll
      for (int nt2 = 0; nt2 < 2; ++nt2)
        bv8[nt2] = *(const bf16x8*)&sVT[(eh + nt2 * 16 + l16) * 40 + quad * 8];
#pragma unroll
      for (int mt = 0; mt < 2; ++mt)
#pragma unroll
        for (int nt2 = 0; nt2 < 2; ++nt2)
          o_acc[mt][nt2] =
              __builtin_amdgcn_mfma_f32_16x16x32_bf16(ap[mt], bv8[nt2], o_acc[mt][nt2], 0, 0, 0);
    }
  }  // tile loop

  // ---------------- finalize O -> bufx0 (as attn-out, bf16, wave-private cols)
#pragma unroll
  for (int mt = 0; mt < 2; ++mt) {
    float invl[4];
#pragma unroll
    for (int r = 0; r < 4; ++r) invl[r] = 1.f / l_run[mt][r];
#pragma unroll
    for (int nt2 = 0; nt2 < 2; ++nt2)
#pragma unroll
      for (int r = 0; r < 4; ++r)
        bufx0[(mt * 16 + quad * 4 + r) * 264 + eh + nt2 * 16 + l16] =
            f2bf(o_acc[mt][nt2][r] * invl[r]);
  }
  __syncthreads();

  // ---------------- GEMM1: proj = AO @ w_out^T + b_out -> sK0 (bf16)
#pragma unroll
  for (int mt = 0; mt < 2; ++mt) {
    bf16x8 a8[8];
#pragma unroll
    for (int k = 0; k < 8; ++k)
      a8[k] = *(const bf16x8*)&bufx0[(mt * 16 + l16) * 264 + k * 32 + quad * 8];
#pragma unroll
    for (int nt2 = 0; nt2 < 2; ++nt2) {
      const int e0 = w * 32 + nt2 * 16;
      floatx4 acc = fzero;
#pragma unroll
      for (int k = 0; k < 8; ++k) {
        bf16x8 b8 = *(const bf16x8*)&wobf[(c * 256 + e0 + l16) * DIM + k * 32 + quad * 8];
        acc = __builtin_amdgcn_mfma_f32_16x16x32_bf16(a8[k], b8, acc, 0, 0, 0);
      }
      const float bias = b_out[c * 256 + e0 + l16];
#pragma unroll
      for (int r = 0; r < 4; ++r)
        sK0[(mt * 16 + quad * 4 + r) * 264 + e0 + l16] = f2bf(acc[r] + bias);
    }
  }
  __syncthreads();

  // ---------------- GEMM2: out = proj @ w_fuse^T + b_fuse + x
#pragma unroll
  for (int mt = 0; mt < 2; ++mt) {
    bf16x8 a8[8];
#pragma unroll
    for (int k = 0; k < 8; ++k)
      a8[k] = *(const bf16x8*)&sK0[(mt * 16 + l16) * 264 + k * 32 + quad * 8];
#pragma unroll
    for (int nt2 = 0; nt2 < 2; ++nt2) {
      const int e0 = w * 32 + nt2 * 16;
      floatx4 acc = fzero;
#pragma unroll
      for (int k = 0; k < 8; ++k) {
        bf16x8 b8 = *(const bf16x8*)&wfbf[(e0 + l16) * DIM + k * 32 + quad * 8];
        acc = __builtin_amdgcn_mfma_f32_16x16x32_bf16(a8[k], b8, acc, 0, 0, 0);
      }
      const float bfu = b_fuse[e0 + l16];
#pragma unroll
      for (int r = 0; r < 4; ++r) {
        const int row = mt * 16 + quad * 4 + r;
        if (row < CC) {
          const int gp = (b * NPOS + c * CC + row) * DIM + e0 + l16;
          out[gp] = acc[r] + bfu + xf[gp];
        }
      }
    }
  }
}

extern "C" void kernel_launch(void* const* d_in, const int* in_sizes, int n_in,
                              void* d_out, int out_size, void* d_ws, size_t ws_size,
                              hipStream_t stream) {
  const float* x      = (const float*)d_in[0];
  const float* w_in   = (const float*)d_in[1];
  const float* b_in   = (const float*)d_in[2];
  const float* w_out  = (const float*)d_in[3];
  const float* b_out  = (const float*)d_in[4];
  const float* w_fuse = (const float*)d_in[5];
  const float* b_fuse = (const float*)d_in[6];
  float* out = (float*)d_out;

  if (ws_size < (size_t)16384000) return;  // 16.38 MB bf16 scratch (validated bound)

  unsigned short* ws = (unsigned short*)d_ws;
  unsigned short* x_bf  = ws;              // 32*384*256   = 3,145,728
  unsigned short* wi_bf = ws + 3145728;    // 19*768*256   = 3,735,552
  unsigned short* wo_bf = ws + 6881280;    // 19*256*256   = 1,245,184
  unsigned short* wf_bf = ws + 8126464;    // 256*256      = 65,536

  conv_all_kernel<<<8000, 256, 0, stream>>>(x, w_in, w_out, w_fuse, ws);

  (void)hipFuncSetAttribute((const void*)cgca_kernel,
                            hipFuncAttributeMaxDynamicSharedMemorySize, LDS_BYTES);
  cgca_kernel<<<608, 512, LDS_BYTES, stream>>>(x, b_in, b_out, b_fuse, x_bf, wi_bf,
                                               wo_bf, wf_bf, out);
}

// Round 7
// 298.500 us; speedup vs baseline: 1.9784x; 1.2142x over previous
//
#include <hip/hip_runtime.h>

#define CC 19
#define NPOS 361
#define NPAD 384
#define DIM 256
#define TKEY 32
#define NTILES 12

// LDS layout (bytes), double-buffered pipeline, 1 barrier/tile:
//   sQ     : 32 x 264 bf16              = 16896   [0)
//   bufx   : 2 x 32 x 264 bf16          = 33792   [16896)
//   sK     : 2 x 32 x 264 bf16          = 33792   [50688)
//   sVT    : 2 x 272 x 40 bf16          = 43520   [84480)   rows 256..271: ones/zeros
//   sP     : 8 waves x 32 x 40 bf16     = 20480   [128000)
// total = 148480 (<=160KB; 1 block/CU is structural at this reg liveset)
#define LDS_BYTES 148480

using bf16x8 = __attribute__((ext_vector_type(8))) short;
using floatx4 = __attribute__((ext_vector_type(4))) float;

__device__ __forceinline__ unsigned short f2bf(float f) {
  unsigned u = __builtin_bit_cast(unsigned, f);
  u += 0x7fffu + ((u >> 16) & 1u);
  return (unsigned short)(u >> 16);
}

// fused conversion: x (zero-padded 361->384 rows) + all weights, f32 -> bf16
__global__ void conv_all_kernel(const float* __restrict__ x,
                                const float* __restrict__ w_in,
                                const float* __restrict__ w_out,
                                const float* __restrict__ w_fuse,
                                unsigned short* __restrict__ ws) {
  const int j = blockIdx.x * 256 + threadIdx.x;
  float4 v = make_float4(0.f, 0.f, 0.f, 0.f);
  unsigned short* dst;
  if (j < 786432) {
    const int row = j >> 6;
    const int off = (j & 63) << 2;
    const int b = row / NPAD;
    const int r = row - b * NPAD;
    if (r < NPOS) v = *(const float4*)&x[(b * NPOS + r) * DIM + off];
    dst = &ws[row * DIM + off];
  } else if (j < 1720320) {
    const int k = j - 786432;
    v = *(const float4*)&w_in[k << 2];
    dst = &ws[3145728 + (k << 2)];
  } else if (j < 2031616) {
    const int k = j - 1720320;
    v = *(const float4*)&w_out[k << 2];
    dst = &ws[6881280 + (k << 2)];
  } else {
    const int k = j - 2031616;
    v = *(const float4*)&w_fuse[k << 2];
    dst = &ws[8126464 + (k << 2)];
  }
  ushort4 o;
  o.x = f2bf(v.x); o.y = f2bf(v.y); o.z = f2bf(v.z); o.w = f2bf(v.w);
  *(ushort4*)dst = o;
}

// launch_bounds (512,2): VGPR cap 256 -> no spills (R2/R4: capping below the
// natural liveset costs 3x in spill traffic).
__launch_bounds__(512, 2)
__global__ void cgca_kernel(const float* __restrict__ xf,
                            const float* __restrict__ b_in,
                            const float* __restrict__ b_out,
                            const float* __restrict__ b_fuse,
                            const unsigned short* __restrict__ xbf,
                            const unsigned short* __restrict__ wibf,
                            const unsigned short* __restrict__ wobf,
                            const unsigned short* __restrict__ wfbf,
                            float* __restrict__ out) {
  // XCD-aware swizzle: same channel's 32 batches contiguous on one XCD.
  const int bid = blockIdx.x;
  const int xcd = bid & 7;
  const int slot = bid >> 3;
  int c, b;
  if (slot < 64) {
    c = ((slot >> 5) << 3) + xcd;   // channels 0..15
    b = slot & 31;
  } else {
    const int widx = ((slot - 64) << 3) + xcd;  // 0..95
    c = 16 + (widx >> 5);           // channels 16..18
    b = widx & 31;
  }

  const int tid = threadIdx.x;
  const int w = tid >> 6;        // wave 0..7 == head index
  const int lane = tid & 63;
  const int quad = lane >> 4;
  const int l16 = lane & 15;

  extern __shared__ char smem[];
  unsigned short* sQ    = (unsigned short*)(smem);
  unsigned short* bufx0 = (unsigned short*)(smem + 16896);
  unsigned short* bufx1 = (unsigned short*)(smem + 16896 + 16896);
  unsigned short* sK0   = (unsigned short*)(smem + 50688);
  unsigned short* sK1   = (unsigned short*)(smem + 50688 + 16896);
  unsigned short* sVT0  = (unsigned short*)(smem + 84480);
  unsigned short* sVT1  = (unsigned short*)(smem + 84480 + 21760);
  unsigned short* sP    = (unsigned short*)(smem + 128000) + w * 1280;  // 32x40 wave-private

  const float scale = 0.17677669529663687f;  // 1/sqrt(32)
  const floatx4 fzero = {0.f, 0.f, 0.f, 0.f};

  // ones/zero rows 256..271 of both sVT buffers (ones-column trick for l):
  // row 256 = 1.0, rows 257..271 = 0. Written once; K/V stores never touch them.
  for (int i = tid; i < 2 * 16 * 40; i += 512) {
    const int buf = i >= 640;
    const int idx = buf ? (i - 640) : i;
    const int row = idx / 40;
    const int col = idx - row * 40;
    unsigned short val = (row == 0) ? (unsigned short)0x3F80 : (unsigned short)0;
    (buf ? sVT1 : sVT0)[(256 + row) * 40 + col] = val;
  }

  // ---------------- Phase 1: Q = xq @ wq^T + bq (scaled) -> sQ bf16 [32][264]
  {
    const int eh0 = w * 32;
#pragma unroll
    for (int mt = 0; mt < 2; ++mt) {
      const int xrow = b * NPAD + c * CC + mt * 16 + l16;  // zero-padded rows
      bf16x8 a8[8];
#pragma unroll
      for (int k = 0; k < 8; ++k)
        a8[k] = *(const bf16x8*)&xbf[xrow * DIM + k * 32 + quad * 8];
#pragma unroll
      for (int nt2 = 0; nt2 < 2; ++nt2) {
        const int e0 = eh0 + nt2 * 16;
        floatx4 acc = fzero;
#pragma unroll
        for (int k = 0; k < 8; ++k) {
          bf16x8 b8 = *(const bf16x8*)&wibf[(c * 768 + e0 + l16) * DIM + k * 32 + quad * 8];
          acc = __builtin_amdgcn_mfma_f32_16x16x32_bf16(a8[k], b8, acc, 0, 0, 0);
        }
        const float bias = b_in[c * 768 + e0 + l16];
#pragma unroll
        for (int r = 0; r < 4; ++r)
          sQ[(mt * 16 + quad * 4 + r) * 264 + e0 + l16] = f2bf((acc[r] + bias) * scale);
      }
    }
  }

  // KV weight slab -> registers once (loop-invariant across 12 tiles)
  const int wrow0 = c * 768 + 256 + w * 64;
  bf16x8 wreg[4][8];
#pragma unroll
  for (int m4 = 0; m4 < 4; ++m4)
#pragma unroll
    for (int k = 0; k < 8; ++k)
      wreg[m4][k] = *(const bf16x8*)&wibf[(wrow0 + m4 * 16 + l16) * DIM + k * 32 + quad * 8];

  // hoisted KV bias
  float ba[4][4];
#pragma unroll
  for (int m4 = 0; m4 < 4; ++m4) {
    const float4 bv = *(const float4*)&b_in[wrow0 + m4 * 16 + quad * 4];
    ba[m4][0] = bv.x; ba[m4][1] = bv.y; ba[m4][2] = bv.z; ba[m4][3] = bv.w;
  }

  // stage x tile 0 -> bufx0
#pragma unroll
  for (int it = 0; it < 2; ++it) {
    const int cc2 = tid + it * 512;
    const int row = cc2 >> 5;
    const int col = (cc2 & 31) * 8;
    *(bf16x8*)&bufx0[row * 264 + col] = *(const bf16x8*)&xbf[(b * NPAD + row) * DIM + col];
  }

  floatx4 o_acc[2][2];   // O accum (un-normalized)
  floatx4 lacc[2];       // row-sum accum via ones-column MFMA
#pragma unroll
  for (int mt = 0; mt < 2; ++mt) {
#pragma unroll
    for (int nt2 = 0; nt2 < 2; ++nt2) o_acc[mt][nt2] = fzero;
    lacc[mt] = fzero;
  }
  const int eh = w * 32;

  __syncthreads();  // Q in sQ, x(0) staged, ones rows written

  // hoist Q fragments (sQ is read-only from here until the epilogue)
  bf16x8 aqr[2];
#pragma unroll
  for (int mt = 0; mt < 2; ++mt)
    aqr[mt] = *(const bf16x8*)&sQ[(mt * 16 + l16) * 264 + eh + quad * 8];

  for (int t = 0; t < NTILES; ++t) {
    const int t0 = t * TKEY;
    unsigned short* bx  = (t & 1) ? bufx1 : bufx0;
    unsigned short* bxn = (t & 1) ? bufx0 : bufx1;
    unsigned short* sK  = (t & 1) ? sK1 : sK0;
    unsigned short* sVT = (t & 1) ? sVT1 : sVT0;

    // stage x(t+1) -> other buffer
    if (t + 1 < NTILES) {
#pragma unroll
      for (int it = 0; it < 2; ++it) {
        const int cc2 = tid + it * 512;
        const int row = cc2 >> 5;
        const int col = (cc2 & 31) * 8;
        *(bf16x8*)&bxn[row * 264 + col] =
            *(const bf16x8*)&xbf[(b * NPAD + t0 + TKEY + row) * DIM + col];
      }
    }

    // ---------------- KV^T projection from register-resident weights
    {
      floatx4 acc[4][2];
#pragma unroll
      for (int m4 = 0; m4 < 4; ++m4)
#pragma unroll
        for (int n4 = 0; n4 < 2; ++n4) acc[m4][n4] = fzero;

#pragma unroll
      for (int k = 0; k < 8; ++k) {
        bf16x8 bfr[2];
#pragma unroll
        for (int n4 = 0; n4 < 2; ++n4)
          bfr[n4] = *(const bf16x8*)&bx[(n4 * 16 + l16) * 264 + k * 32 + quad * 8];
#pragma unroll
        for (int m4 = 0; m4 < 4; ++m4)
#pragma unroll
          for (int n4 = 0; n4 < 2; ++n4)
            acc[m4][n4] = __builtin_amdgcn_mfma_f32_16x16x32_bf16(wreg[m4][k], bfr[n4],
                                                                  acc[m4][n4], 0, 0, 0);
      }
      // +bias, cvt bf16, store K [key][e] / V^T [e][key]
#pragma unroll
      for (int m4 = 0; m4 < 4; ++m4) {
#pragma unroll
        for (int n4 = 0; n4 < 2; ++n4) {
          const int key = n4 * 16 + l16;
          if (w < 4) {
            const int e0 = w * 64 + m4 * 16 + quad * 4;
            ushort4 pk;
            pk.x = f2bf(acc[m4][n4][0] + ba[m4][0]);
            pk.y = f2bf(acc[m4][n4][1] + ba[m4][1]);
            pk.z = f2bf(acc[m4][n4][2] + ba[m4][2]);
            pk.w = f2bf(acc[m4][n4][3] + ba[m4][3]);
            *(ushort4*)&sK[key * 264 + e0] = pk;
          } else {
            const int e0 = (w - 4) * 64 + m4 * 16 + quad * 4;
#pragma unroll
            for (int r = 0; r < 4; ++r)
              sVT[(e0 + r) * 40 + key] = f2bf(acc[m4][n4][r] + ba[m4][r]);
          }
        }
      }
    }
    __syncthreads();  // the ONE barrier: kv[t] ready

    // ---------------- scores + mask + exp (no online max: |s| bounded) + P
#pragma unroll
    for (int mt = 0; mt < 2; ++mt) {
#pragma unroll
      for (int n4 = 0; n4 < 2; ++n4) {
        const bf16x8 bk = *(const bf16x8*)&sK[(n4 * 16 + l16) * 264 + eh + quad * 8];
        const floatx4 sc = __builtin_amdgcn_mfma_f32_16x16x32_bf16(aqr[mt], bk, fzero, 0, 0, 0);
        const int kabs = t0 + n4 * 16 + l16;
        const unsigned ki = ((unsigned)kabs * 110377u) >> 21;  // kabs/19, kabs<=383
        const unsigned kj = (unsigned)kabs - ki * 19u;
#pragma unroll
        for (int r = 0; r < 4; ++r) {
          const unsigned j = (unsigned)(mt * 16 + quad * 4 + r);
          const bool ok = (kabs < NPOS) &&
                          (ki == (unsigned)c || kj == (unsigned)c || ki == j || kj == j);
          const float p = ok ? __expf(sc[r]) : 0.f;
          sP[(mt * 16 + quad * 4 + r) * 40 + n4 * 16 + l16] = f2bf(p);
        }
      }
    }

    // ---------------- PV: O += P @ [V | ones] (l accumulates in the ones col)
    {
      bf16x8 ap[2], bv8[2];
#pragma unroll
      for (int mt = 0; mt < 2; ++mt)
        ap[mt] = *(const bf16x8*)&sP[(mt * 16 + l16) * 40 + quad * 8];
#pragma unroll
      for (int nt2 = 0; nt2 < 2; ++nt2)
        bv8[nt2] = *(const bf16x8*)&sVT[(eh + nt2 * 16 + l16) * 40 + quad * 8];
      const bf16x8 bones = *(const bf16x8*)&sVT[(256 + l16) * 40 + quad * 8];
#pragma unroll
      for (int mt = 0; mt < 2; ++mt) {
#pragma unroll
        for (int nt2 = 0; nt2 < 2; ++nt2)
          o_acc[mt][nt2] =
              __builtin_amdgcn_mfma_f32_16x16x32_bf16(ap[mt], bv8[nt2], o_acc[mt][nt2], 0, 0, 0);
        lacc[mt] = __builtin_amdgcn_mfma_f32_16x16x32_bf16(ap[mt], bones, lacc[mt], 0, 0, 0);
      }
    }
  }  // tile loop

  // ---------------- finalize O -> bufx0 (attn-out bf16); l lives in lacc col 0
#pragma unroll
  for (int mt = 0; mt < 2; ++mt) {
    float invl[4];
#pragma unroll
    for (int r = 0; r < 4; ++r) {
      const float l = __shfl(lacc[mt][r], (lane & 48));  // broadcast col-0 lane of this quad
      invl[r] = 1.f / l;
    }
#pragma unroll
    for (int nt2 = 0; nt2 < 2; ++nt2)
#pragma unroll
      for (int r = 0; r < 4; ++r)
        bufx0[(mt * 16 + quad * 4 + r) * 264 + eh + nt2 * 16 + l16] =
            f2bf(o_acc[mt][nt2][r] * invl[r]);
  }
  __syncthreads();

  // ---------------- GEMM1: proj = AO @ w_out^T + b_out -> sK0 (bf16)
#pragma unroll
  for (int mt = 0; mt < 2; ++mt) {
    bf16x8 a8[8];
#pragma unroll
    for (int k = 0; k < 8; ++k)
      a8[k] = *(const bf16x8*)&bufx0[(mt * 16 + l16) * 264 + k * 32 + quad * 8];
#pragma unroll
    for (int nt2 = 0; nt2 < 2; ++nt2) {
      const int e0 = w * 32 + nt2 * 16;
      floatx4 acc = fzero;
#pragma unroll
      for (int k = 0; k < 8; ++k) {
        bf16x8 b8 = *(const bf16x8*)&wobf[(c * 256 + e0 + l16) * DIM + k * 32 + quad * 8];
        acc = __builtin_amdgcn_mfma_f32_16x16x32_bf16(a8[k], b8, acc, 0, 0, 0);
      }
      const float bias = b_out[c * 256 + e0 + l16];
#pragma unroll
      for (int r = 0; r < 4; ++r)
        sK0[(mt * 16 + quad * 4 + r) * 264 + e0 + l16] = f2bf(acc[r] + bias);
    }
  }
  __syncthreads();

  // ---------------- GEMM2: out = proj @ w_fuse^T + b_fuse + x
#pragma unroll
  for (int mt = 0; mt < 2; ++mt) {
    bf16x8 a8[8];
#pragma unroll
    for (int k = 0; k < 8; ++k)
      a8[k] = *(const bf16x8*)&sK0[(mt * 16 + l16) * 264 + k * 32 + quad * 8];
#pragma unroll
    for (int nt2 = 0; nt2 < 2; ++nt2) {
      const int e0 = w * 32 + nt2 * 16;
      floatx4 acc = fzero;
#pragma unroll
      for (int k = 0; k < 8; ++k) {
        bf16x8 b8 = *(const bf16x8*)&wfbf[(e0 + l16) * DIM + k * 32 + quad * 8];
        acc = __builtin_amdgcn_mfma_f32_16x16x32_bf16(a8[k], b8, acc, 0, 0, 0);
      }
      const float bfu = b_fuse[e0 + l16];
#pragma unroll
      for (int r = 0; r < 4; ++r) {
        const int row = mt * 16 + quad * 4 + r;
        if (row < CC) {
          const int gp = (b * NPOS + c * CC + row) * DIM + e0 + l16;
          out[gp] = acc[r] + bfu + xf[gp];
        }
      }
    }
  }
}

extern "C" void kernel_launch(void* const* d_in, const int* in_sizes, int n_in,
                              void* d_out, int out_size, void* d_ws, size_t ws_size,
                              hipStream_t stream) {
  const float* x      = (const float*)d_in[0];
  const float* w_in   = (const float*)d_in[1];
  const float* b_in   = (const float*)d_in[2];
  const float* w_out  = (const float*)d_in[3];
  const float* b_out  = (const float*)d_in[4];
  const float* w_fuse = (const float*)d_in[5];
  const float* b_fuse = (const float*)d_in[6];
  float* out = (float*)d_out;

  if (ws_size < (size_t)16384000) return;  // 16.38 MB bf16 scratch (validated bound)

  unsigned short* ws = (unsigned short*)d_ws;
  unsigned short* x_bf  = ws;              // 32*384*256   = 3,145,728
  unsigned short* wi_bf = ws + 3145728;    // 19*768*256   = 3,735,552
  unsigned short* wo_bf = ws + 6881280;    // 19*256*256   = 1,245,184
  unsigned short* wf_bf = ws + 8126464;    // 256*256      = 65,536

  conv_all_kernel<<<8000, 256, 0, stream>>>(x, w_in, w_out, w_fuse, ws);

  (void)hipFuncSetAttribute((const void*)cgca_kernel,
                            hipFuncAttributeMaxDynamicSharedMemorySize, LDS_BYTES);
  cgca_kernel<<<608, 512, LDS_BYTES, stream>>>(x, b_in, b_out, b_fuse, x_bf, wi_bf,
                                               wo_bf, wf_bf, out);
}